// Round 3
// baseline (997.130 us; speedup 1.0000x reference)
//
#include <hip/hip_runtime.h>

#define E_EDGES 800000
#define NN 50000
#define C 128
#define EAC 70
#define EF 65
#define SCALE 0.08838834764831845f  /* 128^-0.5 */

typedef __attribute__((ext_vector_type(8))) short short8;
typedef __attribute__((ext_vector_type(4))) float floatx4;

__device__ __forceinline__ unsigned short f2bf(float f) {
  unsigned u = __builtin_bit_cast(unsigned, f);
  unsigned r = (u + 0x7FFFu + ((u >> 16) & 1u)) >> 16;
  return (unsigned short)r;
}
__device__ __forceinline__ float bf2f(unsigned short h) {
  unsigned u = ((unsigned)h) << 16;
  return __builtin_bit_cast(float, u);
}

// ---------------- fused setup: wm | prep | hist ------------------------------
__global__ void setup_kernel(const float* __restrict__ Wf, const float* __restrict__ Wq,
                             const float* __restrict__ Wk, const float* __restrict__ Wa,
                             const int* __restrict__ src, unsigned short* __restrict__ wfrag,
                             float* __restrict__ Wm, int* __restrict__ deg) {
  int b = blockIdx.x;
  if (b < 64) {
    int idx = b * 256 + threadIdx.x;          // 16384 = C*C exactly
    int r = idx >> 7, d = idx & 127;
    const float* wq = Wq + (size_t)r * C;
    const float* wk = Wk + (size_t)d * C;
    float s = 0.f;
    for (int c = 0; c < C; ++c) s += wq[c] * Wa[c] * wk[c];
    Wm[idx] = s * SCALE;
  } else if (b < 240) {
    int idx = (b - 64) * 256 + threadIdx.x;   // 45056 exactly
    int arr = idx >> 14;
    int rem = idx & 16383;
    int j = rem & 7;
    int l = (rem >> 3) & 63;
    int st = rem >> 9;
    int s = st >> 3, t = st & 7;
    int k = s * 32 + (l >> 4) * 8 + j;
    int n = t * 16 + (l & 15);
    float v;
    if (arr == 0)      v = Wf[k * C + n] + Wf[(256 + k) * C + n];
    else if (arr == 1) v = Wf[(128 + k) * C + n] - Wf[(256 + k) * C + n];
    else               v = (k < EF) ? Wf[(384 + k) * C + n] : 0.f;
    wfrag[idx] = f2bf(v);
  } else {
    int e = (b - 240) * 256 + threadIdx.x;    // 800000 exactly
    atomicAdd(deg + src[e], 1);
  }
}

// ---------------- M = bf16(x @ Wm) and XB = bf16(x) --------------------------
__global__ __launch_bounds__(256) void m_kernel(const float* __restrict__ x,
                                                const float* __restrict__ Wm,
                                                unsigned short* __restrict__ M,
                                                unsigned short* __restrict__ XB) {
  __shared__ float rows[32][129];
  int b0 = blockIdx.x * 32;
  for (int idx = threadIdx.x; idx < 32 * 128; idx += 256) {
    int r = idx >> 7, i = idx & 127;
    int n = b0 + r;
    float v = 0.f;
    if (n < NN) {
      v = x[(size_t)n * C + i];
      XB[(size_t)n * C + i] = f2bf(v);
    }
    rows[r][i] = v;
  }
  __syncthreads();
  int tr = threadIdx.x >> 4;
  int tc = threadIdx.x & 15;
  floatx4 a00 = (floatx4){0,0,0,0}, a01 = a00, a10 = a00, a11 = a00;
  for (int i = 0; i < C; ++i) {
    float r0 = rows[tr * 2][i], r1 = rows[tr * 2 + 1][i];
    const floatx4* wr = (const floatx4*)(Wm + (size_t)i * C + tc * 8);
    floatx4 w0 = wr[0], w1 = wr[1];
    a00 += w0 * r0; a01 += w1 * r0;
    a10 += w0 * r1; a11 += w1 * r1;
  }
  int n0 = b0 + tr * 2;
  for (int rr = 0; rr < 2; ++rr) {
    int n = n0 + rr;
    if (n < NN) {
      floatx4 v0 = rr ? a10 : a00, v1 = rr ? a11 : a01;
      short8 o;
      for (int j = 0; j < 4; ++j) { o[j] = (short)f2bf(v0[j]); o[4 + j] = (short)f2bf(v1[j]); }
      *(short8*)(M + (size_t)n * C + tc * 8) = o;
    }
  }
}

// ---------------- CSR scan + position scatter --------------------------------
__global__ __launch_bounds__(1024) void scan_kernel(const int* __restrict__ deg,
                                                    int* __restrict__ offs) {
  __shared__ int buf[1024];
  const int CH = 49;
  int t = threadIdx.x, base = t * CH;
  int s = 0;
  for (int k = 0; k < CH; ++k)
    if (base + k < NN) s += deg[base + k];
  buf[t] = s;
  __syncthreads();
  for (int d = 1; d < 1024; d <<= 1) {
    int add = (t >= d) ? buf[t - d] : 0;
    __syncthreads();
    buf[t] += add;
    __syncthreads();
  }
  int excl = buf[t] - s;
  for (int k = 0; k < CH; ++k)
    if (base + k < NN) { offs[base + k] = excl; excl += deg[base + k]; }
}

// one scattered 16B store per edge instead of three scattered 4B stores
__global__ void pos_kernel(const int* __restrict__ src, const int* __restrict__ tgt,
                           const int* __restrict__ offs, int* __restrict__ cursor,
                           int4* __restrict__ rec) {
  int e = blockIdx.x * 256 + threadIdx.x;   // 800000 exactly
  int r = src[e];
  int p = offs[r] + atomicAdd(cursor + r, 1);
  rec[p] = make_int4(r, tgt[e], e, 0);
}

// ---------------- edge kernel: 16 edges/wave, CSR order ----------------------
// f, a, cf = exp(tanh(f.M[src])); wave-local segmented reduction over the 16
// CSR-sorted edges; flush ~2 partial rows/wave into P / a_sum via atomics.
// 8 blocks/CU (VGPR 48, LDS 18.4KB) for latency hiding on the random gathers.
__global__ __launch_bounds__(256, 8) void edge_kernel(
    const unsigned short* __restrict__ XB, const float* __restrict__ ea,
    const float* __restrict__ bfv, const unsigned short* __restrict__ wfrag,
    const int4* __restrict__ rec, const unsigned short* __restrict__ M,
    float* __restrict__ P, float* __restrict__ a_sum) {
  __shared__ unsigned short f_lds[4][16][136];
  __shared__ float mask_lds[4][16];
  __shared__ float a_lds[4][16];
  __shared__ int src_lds[4][16];
  const int l = threadIdx.x & 63;
  const int w = threadIdx.x >> 6;
  const int lo = l & 15, quad = l >> 4;
  const int e0 = (blockIdx.x * 4 + w) * 16;

  const short8* WF1 = (const short8*)wfrag;
  const short8* WF2 = (const short8*)(wfrag + 16384);
  const short8* WF4 = (const short8*)(wfrag + 32768);

  // A-fragment rows (m = lo): edge at CSR position p
  int p = e0 + lo;
  int4 rp = rec[p];
  int sp = rp.x, tp = rp.y, ep = rp.z;
  if (l < 16) src_lds[w][l] = sp;   // wave-local, in-order DS pipe

  short8 niF[4], njF[4], eaF[3];
  {
    const short8* xr = (const short8*)(XB + (size_t)sp * C);
    const short8* yr = (const short8*)(XB + (size_t)tp * C);
    for (int s = 0; s < 4; ++s) { niF[s] = xr[s * 4 + quad]; njF[s] = yr[s * 4 + quad]; }
  }
  {
    const float* er = ea + (size_t)ep * EAC;     // 280B rows: 8B aligned
    const float2* ca = (const float2*)(er + quad * 8);
    const float2* cb = (const float2*)(er + 32 + quad * 8);
    float2 a0 = ca[0], a1 = ca[1], a2 = ca[2], a3 = ca[3];
    float2 b0 = cb[0], b1 = cb[1], b2 = cb[2], b3 = cb[3];
    short8 t0, t1, t2;
    t0[0] = (short)f2bf(a0.x); t0[1] = (short)f2bf(a0.y);
    t0[2] = (short)f2bf(a1.x); t0[3] = (short)f2bf(a1.y);
    t0[4] = (short)f2bf(a2.x); t0[5] = (short)f2bf(a2.y);
    t0[6] = (short)f2bf(a3.x); t0[7] = (short)f2bf(a3.y);
    t1[0] = (short)f2bf(b0.x); t1[1] = (short)f2bf(b0.y);
    t1[2] = (short)f2bf(b1.x); t1[3] = (short)f2bf(b1.y);
    t1[4] = (short)f2bf(b2.x); t1[5] = (short)f2bf(b2.y);
    t1[6] = (short)f2bf(b3.x); t1[7] = (short)f2bf(b3.y);
    for (int j = 0; j < 8; ++j) t2[j] = 0;
    if (quad == 0) {
      t2[0] = (short)f2bf(er[64]);
      mask_lds[w][lo] = (a0.x < 8.f) ? 1.f : 0.f;
    }
    eaF[0] = t0; eaF[1] = t1; eaF[2] = t2;
  }

  // C-layout metadata (row = quad*4+i at CSR position e0+quad*4+i)
  float maskv[4];
  int srcRow[4];
  for (int i = 0; i < 4; ++i) {
    maskv[i] = mask_lds[w][quad * 4 + i];   // wave-local RAW via in-order DS pipe
    srcRow[i] = src_lds[w][quad * 4 + i];
  }

  // f = elu(ni@WF1 + nj@WF2 + ea@WF4 + bf) * mask -> LDS (bf16)
  for (int t = 0; t < 8; ++t) {
    floatx4 acc = (floatx4){0.f, 0.f, 0.f, 0.f};
    for (int s = 0; s < 4; ++s)
      acc = __builtin_amdgcn_mfma_f32_16x16x32_bf16(niF[s], WF1[(s * 8 + t) * 64 + l], acc, 0, 0, 0);
    for (int s = 0; s < 4; ++s)
      acc = __builtin_amdgcn_mfma_f32_16x16x32_bf16(njF[s], WF2[(s * 8 + t) * 64 + l], acc, 0, 0, 0);
    for (int s = 0; s < 3; ++s)
      acc = __builtin_amdgcn_mfma_f32_16x16x32_bf16(eaF[s], WF4[(s * 8 + t) * 64 + l], acc, 0, 0, 0);
    float bias = bfv[lo + 16 * t];
    for (int i = 0; i < 4; ++i) {
      float v = acc[i] + bias;            // C/D: row=quad*4+i, col=lo+16t
      v = v > 0.f ? v : expm1f(v);
      v *= maskv[i];
      f_lds[w][quad * 4 + i][lo + 16 * t] = f2bf(v);
    }
  }

  // a = f . M[src]; coeff = exp(tanh(a)); zv = coeff*f back into f_lds (bf16)
  for (int i = 0; i < 4; ++i) {
    const short8 fv = *(const short8*)&f_lds[w][quad * 4 + i][lo * 8];
    const short8 mv = *(const short8*)(M + (size_t)srcRow[i] * C + lo * 8);
    float d = 0.f;
    for (int j = 0; j < 8; ++j)
      d += bf2f((unsigned short)fv[j]) * bf2f((unsigned short)mv[j]);
    d += __shfl_xor(d, 1);
    d += __shfl_xor(d, 2);
    d += __shfl_xor(d, 4);
    d += __shfl_xor(d, 8);
    float a = tanhf(d);                   // Wm includes the 1/sqrt(C) scale
    float cf = expf(a);
    short8 zv;
    for (int j = 0; j < 8; ++j) zv[j] = (short)f2bf(cf * bf2f((unsigned short)fv[j]));
    *(short8*)&f_lds[w][quad * 4 + i][lo * 8] = zv;
    if (lo == 0) a_lds[w][quad * 4 + i] = a;
  }

  // wave-local segmented reduction over the 16 CSR-sorted rows.
  // src sequence is non-decreasing; branch is wave-uniform (readfirstlane).
  {
    const int col = l << 1;
    float acc0 = 0.f, acc1 = 0.f, accA = 0.f;
    int cur = __builtin_amdgcn_readfirstlane(src_lds[w][0]);
#pragma unroll
    for (int r = 0; r < 16; ++r) {
      int s_r = __builtin_amdgcn_readfirstlane(src_lds[w][r]);
      if (s_r != cur) {
        float* pr = P + (size_t)cur * C + col;
        atomicAdd(pr, acc0);
        atomicAdd(pr + 1, acc1);
        if (l == 0) atomicAdd(a_sum + cur, accA);
        acc0 = acc1 = accA = 0.f;
        cur = s_r;
      }
      unsigned v = *(const unsigned*)&f_lds[w][r][col];
      acc0 += bf2f((unsigned short)(v & 0xFFFFu));
      acc1 += bf2f((unsigned short)(v >> 16));
      accA += a_lds[w][r];
    }
    float* pr = P + (size_t)cur * C + col;
    atomicAdd(pr, acc0);
    atomicAdd(pr + 1, acc1);
    if (l == 0) atomicAdd(a_sum + cur, accA);
  }
}

// ---------------- dense node update: out = (x + exp(-a_sum)*P) @ Wu + bu -----
__global__ __launch_bounds__(256) void node_kernel(
    const float* __restrict__ x, const float* __restrict__ P,
    const float* __restrict__ a_sum, const float* __restrict__ Wu,
    const float* __restrict__ bu, float* __restrict__ out) {
  __shared__ float rows[32][129];
  int b0 = blockIdx.x * 32;
  for (int idx = threadIdx.x; idx < 32 * 128; idx += 256) {
    int r = idx >> 7, i = idx & 127;
    int n = b0 + r;
    float v = 0.f;
    if (n < NN) v = x[(size_t)n * C + i] + expf(-a_sum[n]) * P[(size_t)n * C + i];
    rows[r][i] = v;
  }
  __syncthreads();
  int tr = threadIdx.x >> 4;
  int tc = threadIdx.x & 15;
  floatx4 a00 = (floatx4){0,0,0,0}, a01 = a00, a10 = a00, a11 = a00;
  for (int i = 0; i < C; ++i) {
    float r0 = rows[tr * 2][i], r1 = rows[tr * 2 + 1][i];
    const floatx4* wr = (const floatx4*)(Wu + (size_t)i * C + tc * 8);
    floatx4 w0 = wr[0], w1 = wr[1];
    a00 += w0 * r0; a01 += w1 * r0;
    a10 += w0 * r1; a11 += w1 * r1;
  }
  const floatx4* bv = (const floatx4*)(bu + tc * 8);
  floatx4 bb0 = bv[0], bb1 = bv[1];
  int n0 = b0 + tr * 2;
  if (n0 < NN) {
    floatx4* o = (floatx4*)(out + (size_t)n0 * C + tc * 8);
    o[0] = a00 + bb0; o[1] = a01 + bb1;
  }
  if (n0 + 1 < NN) {
    floatx4* o = (floatx4*)(out + (size_t)(n0 + 1) * C + tc * 8);
    o[0] = a10 + bb0; o[1] = a11 + bb1;
  }
}

// ---------------- fallback: natural-order edge kernel with atomic scatter ----
__global__ __launch_bounds__(256, 4) void fb_edge_kernel(
    const float* __restrict__ x, const int* __restrict__ src,
    const int* __restrict__ tgt, const float* __restrict__ ea,
    const float* __restrict__ bfv, const unsigned short* __restrict__ wfrag,
    const unsigned short* __restrict__ M, float* __restrict__ a_sum,
    float* __restrict__ P) {
  __shared__ unsigned short f_lds[4][16][136];
  __shared__ float mask_lds[4][16];
  const int l = threadIdx.x & 63;
  const int w = threadIdx.x >> 6;
  const int lo = l & 15, quad = l >> 4;
  const int e0 = (blockIdx.x * 4 + w) * 16;
  const short8* WF1 = (const short8*)wfrag;
  const short8* WF2 = (const short8*)(wfrag + 16384);
  const short8* WF4 = (const short8*)(wfrag + 32768);

  int p = e0 + lo;
  int sp = src[p], tp = tgt[p];
  short8 niF[4], njF[4], eaF[3];
  {
    const float* xr = x + (size_t)sp * C;
    const float* yr = x + (size_t)tp * C;
    for (int s = 0; s < 4; ++s) {
      int kb = s * 32 + quad * 8;
      const floatx4* xv = (const floatx4*)(xr + kb);
      const floatx4* yv = (const floatx4*)(yr + kb);
      floatx4 x0 = xv[0], x1 = xv[1], y0 = yv[0], y1 = yv[1];
      short8 a, b;
      for (int j = 0; j < 4; ++j) { a[j] = (short)f2bf(x0[j]); a[4 + j] = (short)f2bf(x1[j]); }
      for (int j = 0; j < 4; ++j) { b[j] = (short)f2bf(y0[j]); b[4 + j] = (short)f2bf(y1[j]); }
      niF[s] = a; njF[s] = b;
    }
    const float* er = ea + (size_t)p * EAC;
    const float2* ca = (const float2*)(er + quad * 8);
    const float2* cb = (const float2*)(er + 32 + quad * 8);
    float2 a0 = ca[0], a1 = ca[1], a2 = ca[2], a3 = ca[3];
    float2 b0 = cb[0], b1 = cb[1], b2 = cb[2], b3 = cb[3];
    short8 t0, t1, t2;
    t0[0] = (short)f2bf(a0.x); t0[1] = (short)f2bf(a0.y);
    t0[2] = (short)f2bf(a1.x); t0[3] = (short)f2bf(a1.y);
    t0[4] = (short)f2bf(a2.x); t0[5] = (short)f2bf(a2.y);
    t0[6] = (short)f2bf(a3.x); t0[7] = (short)f2bf(a3.y);
    t1[0] = (short)f2bf(b0.x); t1[1] = (short)f2bf(b0.y);
    t1[2] = (short)f2bf(b1.x); t1[3] = (short)f2bf(b1.y);
    t1[4] = (short)f2bf(b2.x); t1[5] = (short)f2bf(b2.y);
    t1[6] = (short)f2bf(b3.x); t1[7] = (short)f2bf(b3.y);
    for (int j = 0; j < 8; ++j) t2[j] = 0;
    if (quad == 0) {
      t2[0] = (short)f2bf(er[64]);
      mask_lds[w][lo] = (a0.x < 8.f) ? 1.f : 0.f;
    }
    eaF[0] = t0; eaF[1] = t1; eaF[2] = t2;
  }
  float maskv[4];
  int srcRow[4];
  for (int i = 0; i < 4; ++i) {
    maskv[i] = mask_lds[w][quad * 4 + i];
    srcRow[i] = src[e0 + quad * 4 + i];
  }
  for (int t = 0; t < 8; ++t) {
    floatx4 acc = (floatx4){0.f, 0.f, 0.f, 0.f};
    for (int s = 0; s < 4; ++s)
      acc = __builtin_amdgcn_mfma_f32_16x16x32_bf16(niF[s], WF1[(s * 8 + t) * 64 + l], acc, 0, 0, 0);
    for (int s = 0; s < 4; ++s)
      acc = __builtin_amdgcn_mfma_f32_16x16x32_bf16(njF[s], WF2[(s * 8 + t) * 64 + l], acc, 0, 0, 0);
    for (int s = 0; s < 3; ++s)
      acc = __builtin_amdgcn_mfma_f32_16x16x32_bf16(eaF[s], WF4[(s * 8 + t) * 64 + l], acc, 0, 0, 0);
    float bias = bfv[lo + 16 * t];
    for (int i = 0; i < 4; ++i) {
      float v = acc[i] + bias;
      v = v > 0.f ? v : expm1f(v);
      v *= maskv[i];
      f_lds[w][quad * 4 + i][lo + 16 * t] = f2bf(v);
    }
  }
  for (int i = 0; i < 4; ++i) {
    const short8 fv = *(const short8*)&f_lds[w][quad * 4 + i][lo * 8];
    const short8 mv = *(const short8*)(M + (size_t)srcRow[i] * C + lo * 8);
    float d = 0.f;
    for (int j = 0; j < 8; ++j)
      d += bf2f((unsigned short)fv[j]) * bf2f((unsigned short)mv[j]);
    d += __shfl_xor(d, 1);
    d += __shfl_xor(d, 2);
    d += __shfl_xor(d, 4);
    d += __shfl_xor(d, 8);
    float a = tanhf(d);
    float cf = expf(a);
    if (lo == 0) atomicAdd(a_sum + srcRow[i], a);
    float* Prow = P + (size_t)srcRow[i] * C;
    for (int j = 0; j < 8; ++j)
      atomicAdd(Prow + lo * 8 + j, cf * bf2f((unsigned short)fv[j]));
  }
}

extern "C" void kernel_launch(void* const* d_in, const int* in_sizes, int n_in,
                              void* d_out, int out_size, void* d_ws, size_t ws_size,
                              hipStream_t stream) {
  const float* x  = (const float*)d_in[0];
  const int*   ei = (const int*)d_in[1];
  const float* ea = (const float*)d_in[2];
  const float* Wf = (const float*)d_in[3];
  const float* bf = (const float*)d_in[4];
  const float* Wq = (const float*)d_in[5];
  const float* Wk = (const float*)d_in[6];
  const float* Wa = (const float*)d_in[7];
  const float* Wu = (const float*)d_in[8];
  const float* bu = (const float*)d_in[9];
  float* out = (float*)d_out;
  const int* src = ei;
  const int* tgt = ei + E_EDGES;

  size_t off = 0;
  auto take = [&](size_t n) { size_t r = off; off += (n + 255) & ~(size_t)255; return r; };
  // P, a_sum, deg, cursor contiguous -> single memset
  size_t oP    = take((size_t)NN * C * 4);        // 25.6 MB
  size_t oAs   = take((size_t)NN * 4);
  size_t oDeg  = take((size_t)NN * 4);
  size_t oCur  = take((size_t)NN * 4);
  size_t oOffs = take((size_t)NN * 4);
  size_t oRec  = take((size_t)E_EDGES * 16);      // packed {src,tgt,e,0}
  size_t oWfr  = take((size_t)45056 * 2);
  size_t oWm   = take((size_t)C * C * 4);
  size_t oM    = take((size_t)NN * C * 2);
  size_t oXB   = take((size_t)NN * C * 2);
  size_t need = off;

  if (ws_size >= need) {
    float* P = (float*)((char*)d_ws + oP);
    float* a_sum = (float*)((char*)d_ws + oAs);
    int* deg = (int*)((char*)d_ws + oDeg);
    int* cursor = (int*)((char*)d_ws + oCur);
    int* offs = (int*)((char*)d_ws + oOffs);
    int4* rec = (int4*)((char*)d_ws + oRec);
    unsigned short* wfrag = (unsigned short*)((char*)d_ws + oWfr);
    float* Wm = (float*)((char*)d_ws + oWm);
    unsigned short* M = (unsigned short*)((char*)d_ws + oM);
    unsigned short* XB = (unsigned short*)((char*)d_ws + oXB);

    hipMemsetAsync(P, 0, oOffs - oP, stream);   // P + a_sum + deg + cursor
    setup_kernel<<<3365, 256, 0, stream>>>(Wf, Wq, Wk, Wa, src, wfrag, Wm, deg);
    m_kernel<<<(NN + 31) / 32, 256, 0, stream>>>(x, Wm, M, XB);
    scan_kernel<<<1, 1024, 0, stream>>>(deg, offs);
    pos_kernel<<<E_EDGES / 256, 256, 0, stream>>>(src, tgt, offs, cursor, rec);
    edge_kernel<<<E_EDGES / 64, 256, 0, stream>>>(XB, ea, bf, wfrag, rec, M, P, a_sum);
    node_kernel<<<(NN + 31) / 32, 256, 0, stream>>>(x, P, a_sum, Wu, bu, out);
  } else {
    size_t f = 0;
    auto tk = [&](size_t n) { size_t r = f; f += (n + 255) & ~(size_t)255; return r; };
    size_t fP = tk((size_t)NN * C * 4);
    size_t fAs = tk((size_t)NN * 4);
    size_t fDeg = tk((size_t)NN * 4);
    size_t fWfr = tk((size_t)45056 * 2);
    size_t fWm = tk((size_t)C * C * 4);
    size_t fM = tk((size_t)NN * C * 2);
    float* P = (float*)((char*)d_ws + fP);
    float* a_sum = (float*)((char*)d_ws + fAs);
    int* deg = (int*)((char*)d_ws + fDeg);
    unsigned short* wfrag = (unsigned short*)((char*)d_ws + fWfr);
    float* Wm = (float*)((char*)d_ws + fWm);
    unsigned short* M = (unsigned short*)((char*)d_ws + fM);
    hipMemsetAsync(P, 0, (size_t)NN * C * 4 + 256 + NN * 4, stream);
    setup_kernel<<<3365, 256, 0, stream>>>(Wf, Wq, Wk, Wa, src, wfrag, Wm, deg);
    m_kernel<<<(NN + 31) / 32, 256, 0, stream>>>(x, Wm, M, (unsigned short*)P);
    hipMemsetAsync(P, 0, (size_t)NN * C * 4, stream);  // re-zero P after XB scribble
    fb_edge_kernel<<<E_EDGES / 64, 256, 0, stream>>>(x, src, tgt, ea, bf, wfrag, M,
                                                     a_sum, P);
    node_kernel<<<(NN + 31) / 32, 256, 0, stream>>>(x, P, a_sum, Wu, bu, out);
  }
}

// Round 5
// 854.813 us; speedup vs baseline: 1.1665x; 1.1665x over previous
//
#include <hip/hip_runtime.h>

#define E_EDGES 800000
#define NN 50000
#define C 128
#define EAC 70
#define EF 65
#define SCALE 0.08838834764831845f  /* 128^-0.5 */

typedef __attribute__((ext_vector_type(8))) short short8;
typedef __attribute__((ext_vector_type(4))) float floatx4;

__device__ __forceinline__ unsigned short f2bf(float f) {
  unsigned u = __builtin_bit_cast(unsigned, f);
  unsigned r = (u + 0x7FFFu + ((u >> 16) & 1u)) >> 16;
  return (unsigned short)r;
}
__device__ __forceinline__ float bf2f(unsigned short h) {
  unsigned u = ((unsigned)h) << 16;
  return __builtin_bit_cast(float, u);
}

// packed bf16x2 atomic add: one L2 transaction for two columns
__device__ __forceinline__ void atomic_pk_add_bf16(unsigned short* p, float lo, float hi) {
  unsigned pk = (unsigned)f2bf(lo) | ((unsigned)f2bf(hi) << 16);
  asm volatile("global_atomic_pk_add_bf16 %0, %1, off"
               :: "v"((unsigned long long)(uintptr_t)p), "v"(pk) : "memory");
}

// ---------------- fused setup: wm | prep | hist ------------------------------
__global__ void setup_kernel(const float* __restrict__ Wf, const float* __restrict__ Wq,
                             const float* __restrict__ Wk, const float* __restrict__ Wa,
                             const int* __restrict__ src, unsigned short* __restrict__ wfrag,
                             float* __restrict__ Wm, int* __restrict__ deg) {
  int b = blockIdx.x;
  if (b < 64) {
    int idx = b * 256 + threadIdx.x;          // 16384 = C*C exactly
    int r = idx >> 7, d = idx & 127;
    const float* wq = Wq + (size_t)r * C;
    const float* wk = Wk + (size_t)d * C;
    float s = 0.f;
    for (int c = 0; c < C; ++c) s += wq[c] * Wa[c] * wk[c];
    Wm[idx] = s * SCALE;
  } else if (b < 240) {
    int idx = (b - 64) * 256 + threadIdx.x;   // 45056 exactly
    int arr = idx >> 14;
    int rem = idx & 16383;
    int j = rem & 7;
    int l = (rem >> 3) & 63;
    int st = rem >> 9;
    int s = st >> 3, t = st & 7;
    int k = s * 32 + (l >> 4) * 8 + j;
    int n = t * 16 + (l & 15);
    float v;
    if (arr == 0)      v = Wf[k * C + n] + Wf[(256 + k) * C + n];
    else if (arr == 1) v = Wf[(128 + k) * C + n] - Wf[(256 + k) * C + n];
    else               v = (k < EF) ? Wf[(384 + k) * C + n] : 0.f;
    wfrag[idx] = f2bf(v);
  } else {
    int e = (b - 240) * 256 + threadIdx.x;    // 800000 exactly
    atomicAdd(deg + src[e], 1);
  }
}

// ---------------- M = bf16(x @ Wm) and XB = bf16(x) --------------------------
__global__ __launch_bounds__(256) void m_kernel(const float* __restrict__ x,
                                                const float* __restrict__ Wm,
                                                unsigned short* __restrict__ M,
                                                unsigned short* __restrict__ XB) {
  __shared__ float rows[32][129];
  int b0 = blockIdx.x * 32;
  for (int idx = threadIdx.x; idx < 32 * 128; idx += 256) {
    int r = idx >> 7, i = idx & 127;
    int n = b0 + r;
    float v = 0.f;
    if (n < NN) {
      v = x[(size_t)n * C + i];
      XB[(size_t)n * C + i] = f2bf(v);
    }
    rows[r][i] = v;
  }
  __syncthreads();
  int tr = threadIdx.x >> 4;
  int tc = threadIdx.x & 15;
  floatx4 a00 = (floatx4){0,0,0,0}, a01 = a00, a10 = a00, a11 = a00;
  for (int i = 0; i < C; ++i) {
    float r0 = rows[tr * 2][i], r1 = rows[tr * 2 + 1][i];
    const floatx4* wr = (const floatx4*)(Wm + (size_t)i * C + tc * 8);
    floatx4 w0 = wr[0], w1 = wr[1];
    a00 += w0 * r0; a01 += w1 * r0;
    a10 += w0 * r1; a11 += w1 * r1;
  }
  int n0 = b0 + tr * 2;
  for (int rr = 0; rr < 2; ++rr) {
    int n = n0 + rr;
    if (n < NN) {
      floatx4 v0 = rr ? a10 : a00, v1 = rr ? a11 : a01;
      short8 o;
      for (int j = 0; j < 4; ++j) { o[j] = (short)f2bf(v0[j]); o[4 + j] = (short)f2bf(v1[j]); }
      *(short8*)(M + (size_t)n * C + tc * 8) = o;
    }
  }
}

// ---------------- CSR scan + position scatter --------------------------------
__global__ __launch_bounds__(1024) void scan_kernel(const int* __restrict__ deg,
                                                    int* __restrict__ offs) {
  __shared__ int buf[1024];
  const int CH = 49;
  int t = threadIdx.x, base = t * CH;
  int s = 0;
  for (int k = 0; k < CH; ++k)
    if (base + k < NN) s += deg[base + k];
  buf[t] = s;
  __syncthreads();
  for (int d = 1; d < 1024; d <<= 1) {
    int add = (t >= d) ? buf[t - d] : 0;
    __syncthreads();
    buf[t] += add;
    __syncthreads();
  }
  int excl = buf[t] - s;
  for (int k = 0; k < CH; ++k)
    if (base + k < NN) { offs[base + k] = excl; excl += deg[base + k]; }
}

// one scattered 16B store per edge instead of three scattered 4B stores
__global__ void pos_kernel(const int* __restrict__ src, const int* __restrict__ tgt,
                           const int* __restrict__ offs, int* __restrict__ cursor,
                           int4* __restrict__ rec) {
  int e = blockIdx.x * 256 + threadIdx.x;   // 800000 exactly
  int r = src[e];
  int p = offs[r] + atomicAdd(cursor + r, 1);
  rec[p] = make_int4(r, tgt[e], e, 0);
}

// ---------------- edge kernel: 16 edges/wave, CSR order ----------------------
// f, a, cf = exp(tanh(f.M[src])); wave-local segmented reduction over the 16
// CSR-sorted edges; flush partial rows as packed-bf16 atomics (1 txn / 2 cols).
__global__ __launch_bounds__(256, 5) void edge_kernel(
    const unsigned short* __restrict__ XB, const float* __restrict__ ea,
    const float* __restrict__ bfv, const unsigned short* __restrict__ wfrag,
    const int4* __restrict__ rec, const unsigned short* __restrict__ M,
    unsigned short* __restrict__ Pb, float* __restrict__ a_sum) {
  __shared__ unsigned short f_lds[4][16][136];
  __shared__ float mask_lds[4][16];
  __shared__ float2 acf_lds[4][16];       // (a, cf) per CSR row
  __shared__ int src_lds[4][16];
  const int l = threadIdx.x & 63;
  const int w = threadIdx.x >> 6;
  const int lo = l & 15, quad = l >> 4;
  const int e0 = (blockIdx.x * 4 + w) * 16;

  const short8* WF1 = (const short8*)wfrag;
  const short8* WF2 = (const short8*)(wfrag + 16384);
  const short8* WF4 = (const short8*)(wfrag + 32768);

  // A-fragment rows (m = lo): edge at CSR position p
  int p = e0 + lo;
  int4 rp = rec[p];
  int sp = rp.x, tp = rp.y, ep = rp.z;
  if (l < 16) src_lds[w][l] = sp;   // wave-local, in-order DS pipe

  short8 niF[4], njF[4], eaF[3];
  {
    const short8* xr = (const short8*)(XB + (size_t)sp * C);
    const short8* yr = (const short8*)(XB + (size_t)tp * C);
    for (int s = 0; s < 4; ++s) { niF[s] = xr[s * 4 + quad]; njF[s] = yr[s * 4 + quad]; }
  }
  {
    const float* er = ea + (size_t)ep * EAC;     // 280B rows: 8B aligned
    const float2* ca = (const float2*)(er + quad * 8);
    const float2* cb = (const float2*)(er + 32 + quad * 8);
    float2 a0 = ca[0], a1 = ca[1], a2 = ca[2], a3 = ca[3];
    float2 b0 = cb[0], b1 = cb[1], b2 = cb[2], b3 = cb[3];
    short8 t0, t1, t2;
    t0[0] = (short)f2bf(a0.x); t0[1] = (short)f2bf(a0.y);
    t0[2] = (short)f2bf(a1.x); t0[3] = (short)f2bf(a1.y);
    t0[4] = (short)f2bf(a2.x); t0[5] = (short)f2bf(a2.y);
    t0[6] = (short)f2bf(a3.x); t0[7] = (short)f2bf(a3.y);
    t1[0] = (short)f2bf(b0.x); t1[1] = (short)f2bf(b0.y);
    t1[2] = (short)f2bf(b1.x); t1[3] = (short)f2bf(b1.y);
    t1[4] = (short)f2bf(b2.x); t1[5] = (short)f2bf(b2.y);
    t1[6] = (short)f2bf(b3.x); t1[7] = (short)f2bf(b3.y);
    for (int j = 0; j < 8; ++j) t2[j] = 0;
    if (quad == 0) {
      t2[0] = (short)f2bf(er[64]);
      mask_lds[w][lo] = (a0.x < 8.f) ? 1.f : 0.f;
    }
    eaF[0] = t0; eaF[1] = t1; eaF[2] = t2;
  }

  // C-layout metadata (row = quad*4+i at CSR position e0+quad*4+i)
  float maskv[4];
  int srcRow[4];
  for (int i = 0; i < 4; ++i) {
    maskv[i] = mask_lds[w][quad * 4 + i];   // wave-local RAW via in-order DS pipe
    srcRow[i] = src_lds[w][quad * 4 + i];
  }

  // f = elu(ni@WF1 + nj@WF2 + ea@WF4 + bf) * mask -> LDS (bf16)
  for (int t = 0; t < 8; ++t) {
    floatx4 acc = (floatx4){0.f, 0.f, 0.f, 0.f};
    for (int s = 0; s < 4; ++s)
      acc = __builtin_amdgcn_mfma_f32_16x16x32_bf16(niF[s], WF1[(s * 8 + t) * 64 + l], acc, 0, 0, 0);
    for (int s = 0; s < 4; ++s)
      acc = __builtin_amdgcn_mfma_f32_16x16x32_bf16(njF[s], WF2[(s * 8 + t) * 64 + l], acc, 0, 0, 0);
    for (int s = 0; s < 3; ++s)
      acc = __builtin_amdgcn_mfma_f32_16x16x32_bf16(eaF[s], WF4[(s * 8 + t) * 64 + l], acc, 0, 0, 0);
    float bias = bfv[lo + 16 * t];
    for (int i = 0; i < 4; ++i) {
      float v = acc[i] + bias;            // C/D: row=quad*4+i, col=lo+16t
      v = v > 0.f ? v : expm1f(v);
      v *= maskv[i];
      f_lds[w][quad * 4 + i][lo + 16 * t] = f2bf(v);
    }
  }

  // a = f . M[src]; store (a, cf=exp(a)) per row; f stays as-is in LDS
  for (int i = 0; i < 4; ++i) {
    const short8 fv = *(const short8*)&f_lds[w][quad * 4 + i][lo * 8];
    const short8 mv = *(const short8*)(M + (size_t)srcRow[i] * C + lo * 8);
    float d = 0.f;
    for (int j = 0; j < 8; ++j)
      d += bf2f((unsigned short)fv[j]) * bf2f((unsigned short)mv[j]);
    d += __shfl_xor(d, 1);
    d += __shfl_xor(d, 2);
    d += __shfl_xor(d, 4);
    d += __shfl_xor(d, 8);
    float a = tanhf(d);                   // Wm includes the 1/sqrt(C) scale
    if (lo == 0) acf_lds[w][quad * 4 + i] = make_float2(a, expf(a));
  }

  // wave-local segmented reduction over the 16 CSR-sorted rows.
  // src sequence is non-decreasing; branch is wave-uniform (readfirstlane).
  // Each lane owns 2 columns; partial row flushed as ONE pk-bf16 atomic/lane.
  {
    const int col = l << 1;
    float acc0 = 0.f, acc1 = 0.f, accA = 0.f;
    int cur = __builtin_amdgcn_readfirstlane(src_lds[w][0]);
#pragma unroll
    for (int r = 0; r < 16; ++r) {
      int s_r = __builtin_amdgcn_readfirstlane(src_lds[w][r]);
      if (s_r != cur) {
        atomic_pk_add_bf16(Pb + (size_t)cur * C + col, acc0, acc1);
        if (l == 0) atomicAdd(a_sum + cur, accA);
        acc0 = acc1 = accA = 0.f;
        cur = s_r;
      }
      unsigned v = *(const unsigned*)&f_lds[w][r][col];
      float2 acf = acf_lds[w][r];         // broadcast read
      acc0 = fmaf(acf.y, bf2f((unsigned short)(v & 0xFFFFu)), acc0);
      acc1 = fmaf(acf.y, bf2f((unsigned short)(v >> 16)), acc1);
      accA += acf.x;
    }
    atomic_pk_add_bf16(Pb + (size_t)cur * C + col, acc0, acc1);
    if (l == 0) atomicAdd(a_sum + cur, accA);
  }
}

// ---------------- dense node update: out = (x + exp(-a_sum)*P) @ Wu + bu -----
__global__ __launch_bounds__(256) void node_kernel(
    const float* __restrict__ x, const unsigned short* __restrict__ Pb,
    const float* __restrict__ a_sum, const float* __restrict__ Wu,
    const float* __restrict__ bu, float* __restrict__ out) {
  __shared__ float rows[32][129];
  int b0 = blockIdx.x * 32;
  for (int idx = threadIdx.x; idx < 32 * 128; idx += 256) {
    int r = idx >> 7, i = idx & 127;
    int n = b0 + r;
    float v = 0.f;
    if (n < NN) v = x[(size_t)n * C + i] + expf(-a_sum[n]) * bf2f(Pb[(size_t)n * C + i]);
    rows[r][i] = v;
  }
  __syncthreads();
  int tr = threadIdx.x >> 4;
  int tc = threadIdx.x & 15;
  floatx4 a00 = (floatx4){0,0,0,0}, a01 = a00, a10 = a00, a11 = a00;
  for (int i = 0; i < C; ++i) {
    float r0 = rows[tr * 2][i], r1 = rows[tr * 2 + 1][i];
    const floatx4* wr = (const floatx4*)(Wu + (size_t)i * C + tc * 8);
    floatx4 w0 = wr[0], w1 = wr[1];
    a00 += w0 * r0; a01 += w1 * r0;
    a10 += w0 * r1; a11 += w1 * r1;
  }
  const floatx4* bv = (const floatx4*)(bu + tc * 8);
  floatx4 bb0 = bv[0], bb1 = bv[1];
  int n0 = b0 + tr * 2;
  if (n0 < NN) {
    floatx4* o = (floatx4*)(out + (size_t)n0 * C + tc * 8);
    o[0] = a00 + bb0; o[1] = a01 + bb1;
  }
  if (n0 + 1 < NN) {
    floatx4* o = (floatx4*)(out + (size_t)(n0 + 1) * C + tc * 8);
    o[0] = a10 + bb0; o[1] = a11 + bb1;
  }
}

// ---------------- fallback: natural-order edge kernel with atomic scatter ----
__global__ __launch_bounds__(256, 4) void fb_edge_kernel(
    const float* __restrict__ x, const int* __restrict__ src,
    const int* __restrict__ tgt, const float* __restrict__ ea,
    const float* __restrict__ bfv, const unsigned short* __restrict__ wfrag,
    const unsigned short* __restrict__ M, float* __restrict__ a_sum,
    float* __restrict__ P) {
  __shared__ unsigned short f_lds[4][16][136];
  __shared__ float mask_lds[4][16];
  const int l = threadIdx.x & 63;
  const int w = threadIdx.x >> 6;
  const int lo = l & 15, quad = l >> 4;
  const int e0 = (blockIdx.x * 4 + w) * 16;
  const short8* WF1 = (const short8*)wfrag;
  const short8* WF2 = (const short8*)(wfrag + 16384);
  const short8* WF4 = (const short8*)(wfrag + 32768);

  int p = e0 + lo;
  int sp = src[p], tp = tgt[p];
  short8 niF[4], njF[4], eaF[3];
  {
    const float* xr = x + (size_t)sp * C;
    const float* yr = x + (size_t)tp * C;
    for (int s = 0; s < 4; ++s) {
      int kb = s * 32 + quad * 8;
      const floatx4* xv = (const floatx4*)(xr + kb);
      const floatx4* yv = (const floatx4*)(yr + kb);
      floatx4 x0 = xv[0], x1 = xv[1], y0 = yv[0], y1 = yv[1];
      short8 a, b;
      for (int j = 0; j < 4; ++j) { a[j] = (short)f2bf(x0[j]); a[4 + j] = (short)f2bf(x1[j]); }
      for (int j = 0; j < 4; ++j) { b[j] = (short)f2bf(y0[j]); b[4 + j] = (short)f2bf(y1[j]); }
      niF[s] = a; njF[s] = b;
    }
    const float* er = ea + (size_t)p * EAC;
    const float2* ca = (const float2*)(er + quad * 8);
    const float2* cb = (const float2*)(er + 32 + quad * 8);
    float2 a0 = ca[0], a1 = ca[1], a2 = ca[2], a3 = ca[3];
    float2 b0 = cb[0], b1 = cb[1], b2 = cb[2], b3 = cb[3];
    short8 t0, t1, t2;
    t0[0] = (short)f2bf(a0.x); t0[1] = (short)f2bf(a0.y);
    t0[2] = (short)f2bf(a1.x); t0[3] = (short)f2bf(a1.y);
    t0[4] = (short)f2bf(a2.x); t0[5] = (short)f2bf(a2.y);
    t0[6] = (short)f2bf(a3.x); t0[7] = (short)f2bf(a3.y);
    t1[0] = (short)f2bf(b0.x); t1[1] = (short)f2bf(b0.y);
    t1[2] = (short)f2bf(b1.x); t1[3] = (short)f2bf(b1.y);
    t1[4] = (short)f2bf(b2.x); t1[5] = (short)f2bf(b2.y);
    t1[6] = (short)f2bf(b3.x); t1[7] = (short)f2bf(b3.y);
    for (int j = 0; j < 8; ++j) t2[j] = 0;
    if (quad == 0) {
      t2[0] = (short)f2bf(er[64]);
      mask_lds[w][lo] = (a0.x < 8.f) ? 1.f : 0.f;
    }
    eaF[0] = t0; eaF[1] = t1; eaF[2] = t2;
  }
  float maskv[4];
  int srcRow[4];
  for (int i = 0; i < 4; ++i) {
    maskv[i] = mask_lds[w][quad * 4 + i];
    srcRow[i] = src[e0 + quad * 4 + i];
  }
  for (int t = 0; t < 8; ++t) {
    floatx4 acc = (floatx4){0.f, 0.f, 0.f, 0.f};
    for (int s = 0; s < 4; ++s)
      acc = __builtin_amdgcn_mfma_f32_16x16x32_bf16(niF[s], WF1[(s * 8 + t) * 64 + l], acc, 0, 0, 0);
    for (int s = 0; s < 4; ++s)
      acc = __builtin_amdgcn_mfma_f32_16x16x32_bf16(njF[s], WF2[(s * 8 + t) * 64 + l], acc, 0, 0, 0);
    for (int s = 0; s < 3; ++s)
      acc = __builtin_amdgcn_mfma_f32_16x16x32_bf16(eaF[s], WF4[(s * 8 + t) * 64 + l], acc, 0, 0, 0);
    float bias = bfv[lo + 16 * t];
    for (int i = 0; i < 4; ++i) {
      float v = acc[i] + bias;
      v = v > 0.f ? v : expm1f(v);
      v *= maskv[i];
      f_lds[w][quad * 4 + i][lo + 16 * t] = f2bf(v);
    }
  }
  for (int i = 0; i < 4; ++i) {
    const short8 fv = *(const short8*)&f_lds[w][quad * 4 + i][lo * 8];
    const short8 mv = *(const short8*)(M + (size_t)srcRow[i] * C + lo * 8);
    float d = 0.f;
    for (int j = 0; j < 8; ++j)
      d += bf2f((unsigned short)fv[j]) * bf2f((unsigned short)mv[j]);
    d += __shfl_xor(d, 1);
    d += __shfl_xor(d, 2);
    d += __shfl_xor(d, 4);
    d += __shfl_xor(d, 8);
    float a = tanhf(d);
    float cf = expf(a);
    if (lo == 0) atomicAdd(a_sum + srcRow[i], a);
    float* Prow = P + (size_t)srcRow[i] * C;
    for (int j = 0; j < 8; ++j)
      atomicAdd(Prow + lo * 8 + j, cf * bf2f((unsigned short)fv[j]));
  }
}

__global__ __launch_bounds__(256) void fb_node_kernel(
    const float* __restrict__ x, const float* __restrict__ P,
    const float* __restrict__ a_sum, const float* __restrict__ Wu,
    const float* __restrict__ bu, float* __restrict__ out) {
  __shared__ float rows[32][129];
  int b0 = blockIdx.x * 32;
  for (int idx = threadIdx.x; idx < 32 * 128; idx += 256) {
    int r = idx >> 7, i = idx & 127;
    int n = b0 + r;
    float v = 0.f;
    if (n < NN) v = x[(size_t)n * C + i] + expf(-a_sum[n]) * P[(size_t)n * C + i];
    rows[r][i] = v;
  }
  __syncthreads();
  int tr = threadIdx.x >> 4;
  int tc = threadIdx.x & 15;
  floatx4 a00 = (floatx4){0,0,0,0}, a01 = a00, a10 = a00, a11 = a00;
  for (int i = 0; i < C; ++i) {
    float r0 = rows[tr * 2][i], r1 = rows[tr * 2 + 1][i];
    const floatx4* wr = (const floatx4*)(Wu + (size_t)i * C + tc * 8);
    floatx4 w0 = wr[0], w1 = wr[1];
    a00 += w0 * r0; a01 += w1 * r0;
    a10 += w0 * r1; a11 += w1 * r1;
  }
  const floatx4* bv = (const floatx4*)(bu + tc * 8);
  floatx4 bb0 = bv[0], bb1 = bv[1];
  int n0 = b0 + tr * 2;
  if (n0 < NN) {
    floatx4* o = (floatx4*)(out + (size_t)n0 * C + tc * 8);
    o[0] = a00 + bb0; o[1] = a01 + bb1;
  }
  if (n0 + 1 < NN) {
    floatx4* o = (floatx4*)(out + (size_t)(n0 + 1) * C + tc * 8);
    o[0] = a10 + bb0; o[1] = a11 + bb1;
  }
}

extern "C" void kernel_launch(void* const* d_in, const int* in_sizes, int n_in,
                              void* d_out, int out_size, void* d_ws, size_t ws_size,
                              hipStream_t stream) {
  const float* x  = (const float*)d_in[0];
  const int*   ei = (const int*)d_in[1];
  const float* ea = (const float*)d_in[2];
  const float* Wf = (const float*)d_in[3];
  const float* bf = (const float*)d_in[4];
  const float* Wq = (const float*)d_in[5];
  const float* Wk = (const float*)d_in[6];
  const float* Wa = (const float*)d_in[7];
  const float* Wu = (const float*)d_in[8];
  const float* bu = (const float*)d_in[9];
  float* out = (float*)d_out;
  const int* src = ei;
  const int* tgt = ei + E_EDGES;

  size_t off = 0;
  auto take = [&](size_t n) { size_t r = off; off += (n + 255) & ~(size_t)255; return r; };
  // Pb (bf16), a_sum, deg, cursor contiguous -> single memset
  size_t oP    = take((size_t)NN * C * 2);        // 12.8 MB bf16
  size_t oAs   = take((size_t)NN * 4);
  size_t oDeg  = take((size_t)NN * 4);
  size_t oCur  = take((size_t)NN * 4);
  size_t oOffs = take((size_t)NN * 4);
  size_t oRec  = take((size_t)E_EDGES * 16);      // packed {src,tgt,e,0}
  size_t oWfr  = take((size_t)45056 * 2);
  size_t oWm   = take((size_t)C * C * 4);
  size_t oM    = take((size_t)NN * C * 2);
  size_t oXB   = take((size_t)NN * C * 2);
  size_t need = off;

  if (ws_size >= need) {
    unsigned short* Pb = (unsigned short*)((char*)d_ws + oP);
    float* a_sum = (float*)((char*)d_ws + oAs);
    int* deg = (int*)((char*)d_ws + oDeg);
    int* cursor = (int*)((char*)d_ws + oCur);
    int* offs = (int*)((char*)d_ws + oOffs);
    int4* rec = (int4*)((char*)d_ws + oRec);
    unsigned short* wfrag = (unsigned short*)((char*)d_ws + oWfr);
    float* Wm = (float*)((char*)d_ws + oWm);
    unsigned short* M = (unsigned short*)((char*)d_ws + oM);
    unsigned short* XB = (unsigned short*)((char*)d_ws + oXB);

    hipMemsetAsync(Pb, 0, oOffs - oP, stream);   // Pb + a_sum + deg + cursor
    setup_kernel<<<3365, 256, 0, stream>>>(Wf, Wq, Wk, Wa, src, wfrag, Wm, deg);
    m_kernel<<<(NN + 31) / 32, 256, 0, stream>>>(x, Wm, M, XB);
    scan_kernel<<<1, 1024, 0, stream>>>(deg, offs);
    pos_kernel<<<E_EDGES / 256, 256, 0, stream>>>(src, tgt, offs, cursor, rec);
    edge_kernel<<<E_EDGES / 64, 256, 0, stream>>>(XB, ea, bf, wfrag, rec, M, Pb, a_sum);
    node_kernel<<<(NN + 31) / 32, 256, 0, stream>>>(x, Pb, a_sum, Wu, bu, out);
  } else {
    size_t f = 0;
    auto tk = [&](size_t n) { size_t r = f; f += (n + 255) & ~(size_t)255; return r; };
    size_t fP = tk((size_t)NN * C * 4);
    size_t fAs = tk((size_t)NN * 4);
    size_t fDeg = tk((size_t)NN * 4);
    size_t fWfr = tk((size_t)45056 * 2);
    size_t fWm = tk((size_t)C * C * 4);
    size_t fM = tk((size_t)NN * C * 2);
    float* P = (float*)((char*)d_ws + fP);
    float* a_sum = (float*)((char*)d_ws + fAs);
    int* deg = (int*)((char*)d_ws + fDeg);
    unsigned short* wfrag = (unsigned short*)((char*)d_ws + fWfr);
    float* Wm = (float*)((char*)d_ws + fWm);
    unsigned short* M = (unsigned short*)((char*)d_ws + fM);
    hipMemsetAsync(P, 0, (size_t)NN * C * 4 + 256 + NN * 4, stream);
    setup_kernel<<<3365, 256, 0, stream>>>(Wf, Wq, Wk, Wa, src, wfrag, Wm, deg);
    m_kernel<<<(NN + 31) / 32, 256, 0, stream>>>(x, Wm, M, (unsigned short*)P);
    hipMemsetAsync(P, 0, (size_t)NN * C * 4, stream);  // re-zero P after XB scribble
    fb_edge_kernel<<<E_EDGES / 64, 256, 0, stream>>>(x, src, tgt, ea, bf, wfrag, M,
                                                     a_sum, P);
    fb_node_kernel<<<(NN + 31) / 32, 256, 0, stream>>>(x, P, a_sum, Wu, bu, out);
  }
}

// Round 6
// 790.475 us; speedup vs baseline: 1.2614x; 1.0814x over previous
//
#include <hip/hip_runtime.h>

#define E_EDGES 800000
#define NN 50000
#define C 128
#define EAC 70
#define EF 65
#define NB 196               /* ceil(NN/256) */
#define SCALE 0.08838834764831845f  /* 128^-0.5 */

typedef __attribute__((ext_vector_type(8))) short short8;
typedef __attribute__((ext_vector_type(4))) float floatx4;

__device__ __forceinline__ unsigned short f2bf(float f) {
  unsigned u = __builtin_bit_cast(unsigned, f);
  unsigned r = (u + 0x7FFFu + ((u >> 16) & 1u)) >> 16;
  return (unsigned short)r;
}
__device__ __forceinline__ float bf2f(unsigned short h) {
  unsigned u = ((unsigned)h) << 16;
  return __builtin_bit_cast(float, u);
}

// fast transcendentals (v_exp_f32-based); rel err ~1e-6 << bf16 precision
__device__ __forceinline__ float fast_tanh(float x) {
  float xc = fminf(fmaxf(x, -15.f), 15.f);
  float t = __expf(2.f * xc);
  return (t - 1.f) * __builtin_amdgcn_rcpf(t + 1.f);
}
__device__ __forceinline__ float fast_elu(float v) {
  return v > 0.f ? v : (__expf(v) - 1.f);
}

// packed bf16x2 atomic add: one L2 transaction for two columns
__device__ __forceinline__ void atomic_pk_add_bf16(unsigned short* p, float lo, float hi) {
  unsigned pk = (unsigned)f2bf(lo) | ((unsigned)f2bf(hi) << 16);
  asm volatile("global_atomic_pk_add_bf16 %0, %1, off"
               :: "v"((unsigned long long)(uintptr_t)p), "v"(pk) : "memory");
}

// ---------------- fused setup: wm | prep | hist ------------------------------
__global__ void setup_kernel(const float* __restrict__ Wf, const float* __restrict__ Wq,
                             const float* __restrict__ Wk, const float* __restrict__ Wa,
                             const int* __restrict__ src, unsigned short* __restrict__ wfrag,
                             float* __restrict__ Wm, int* __restrict__ deg) {
  int b = blockIdx.x;
  if (b < 64) {
    int idx = b * 256 + threadIdx.x;          // 16384 = C*C exactly
    int r = idx >> 7, d = idx & 127;
    const float* wq = Wq + (size_t)r * C;
    const float* wk = Wk + (size_t)d * C;
    float s = 0.f;
    for (int c = 0; c < C; ++c) s += wq[c] * Wa[c] * wk[c];
    Wm[idx] = s * SCALE;
  } else if (b < 240) {
    int idx = (b - 64) * 256 + threadIdx.x;   // 45056 exactly
    int arr = idx >> 14;
    int rem = idx & 16383;
    int j = rem & 7;
    int l = (rem >> 3) & 63;
    int st = rem >> 9;
    int s = st >> 3, t = st & 7;
    int k = s * 32 + (l >> 4) * 8 + j;
    int n = t * 16 + (l & 15);
    float v;
    if (arr == 0)      v = Wf[k * C + n] + Wf[(256 + k) * C + n];
    else if (arr == 1) v = Wf[(128 + k) * C + n] - Wf[(256 + k) * C + n];
    else               v = (k < EF) ? Wf[(384 + k) * C + n] : 0.f;
    wfrag[idx] = f2bf(v);
  } else {
    int e = (b - 240) * 256 + threadIdx.x;    // 800000 exactly
    atomicAdd(deg + src[e], 1);
  }
}

// ---------------- M = bf16(x @ Wm) and XB = bf16(x) --------------------------
__global__ __launch_bounds__(256) void m_kernel(const float* __restrict__ x,
                                                const float* __restrict__ Wm,
                                                unsigned short* __restrict__ M,
                                                unsigned short* __restrict__ XB) {
  __shared__ float rows[32][129];
  int b0 = blockIdx.x * 32;
  for (int idx = threadIdx.x; idx < 32 * 128; idx += 256) {
    int r = idx >> 7, i = idx & 127;
    int n = b0 + r;
    float v = 0.f;
    if (n < NN) {
      v = x[(size_t)n * C + i];
      XB[(size_t)n * C + i] = f2bf(v);
    }
    rows[r][i] = v;
  }
  __syncthreads();
  int tr = threadIdx.x >> 4;
  int tc = threadIdx.x & 15;
  floatx4 a00 = (floatx4){0,0,0,0}, a01 = a00, a10 = a00, a11 = a00;
  for (int i = 0; i < C; ++i) {
    float r0 = rows[tr * 2][i], r1 = rows[tr * 2 + 1][i];
    const floatx4* wr = (const floatx4*)(Wm + (size_t)i * C + tc * 8);
    floatx4 w0 = wr[0], w1 = wr[1];
    a00 += w0 * r0; a01 += w1 * r0;
    a10 += w0 * r1; a11 += w1 * r1;
  }
  int n0 = b0 + tr * 2;
  for (int rr = 0; rr < 2; ++rr) {
    int n = n0 + rr;
    if (n < NN) {
      floatx4 v0 = rr ? a10 : a00, v1 = rr ? a11 : a01;
      short8 o;
      for (int j = 0; j < 4; ++j) { o[j] = (short)f2bf(v0[j]); o[4 + j] = (short)f2bf(v1[j]); }
      *(short8*)(M + (size_t)n * C + tc * 8) = o;
    }
  }
}

// ---------------- two-level CSR scan (parallel, replaces 1-block scan) -------
__global__ __launch_bounds__(256) void scan1_kernel(const int* __restrict__ deg,
                                                    int* __restrict__ offs,
                                                    int* __restrict__ bsum) {
  __shared__ int buf[256];
  int t = threadIdx.x, n = blockIdx.x * 256 + t;
  int d = (n < NN) ? deg[n] : 0;
  buf[t] = d;
  __syncthreads();
  for (int s = 1; s < 256; s <<= 1) {
    int add = (t >= s) ? buf[t - s] : 0;
    __syncthreads();
    buf[t] += add;
    __syncthreads();
  }
  if (n < NN) offs[n] = buf[t] - d;      // block-local exclusive
  if (t == 255) bsum[blockIdx.x] = buf[255];
}

__global__ __launch_bounds__(256) void scan2_kernel(const int* __restrict__ bsum,
                                                    int* __restrict__ bbase) {
  __shared__ int buf[256];
  int t = threadIdx.x;
  int d = (t < NB) ? bsum[t] : 0;
  buf[t] = d;
  __syncthreads();
  for (int s = 1; s < 256; s <<= 1) {
    int add = (t >= s) ? buf[t - s] : 0;
    __syncthreads();
    buf[t] += add;
    __syncthreads();
  }
  if (t < NB) bbase[t] = buf[t] - d;     // exclusive block base
}

// one scattered 16B store per edge instead of three scattered 4B stores
__global__ void pos_kernel(const int* __restrict__ src, const int* __restrict__ tgt,
                           const int* __restrict__ offs, const int* __restrict__ bbase,
                           int* __restrict__ cursor, int4* __restrict__ rec) {
  int e = blockIdx.x * 256 + threadIdx.x;   // 800000 exactly
  int r = src[e];
  int p = offs[r] + bbase[r >> 8] + atomicAdd(cursor + r, 1);
  rec[p] = make_int4(r, tgt[e], e, 0);
}

// ---------------- edge kernel: 16 edges/wave, CSR order ----------------------
// f, a, cf = exp(tanh(f.M[src])); wave-local segmented reduction over the 16
// CSR-sorted edges; flush partial rows as packed-bf16 atomics (1 txn / 2 cols).
__global__ __launch_bounds__(256, 5) void edge_kernel(
    const unsigned short* __restrict__ XB, const float* __restrict__ ea,
    const float* __restrict__ bfv, const unsigned short* __restrict__ wfrag,
    const int4* __restrict__ rec, const unsigned short* __restrict__ M,
    unsigned short* __restrict__ Pb, float* __restrict__ a_sum) {
  __shared__ unsigned short f_lds[4][16][136];
  __shared__ float mask_lds[4][16];
  __shared__ float2 acf_lds[4][16];       // (a, cf) per CSR row
  __shared__ int src_lds[4][16];
  const int l = threadIdx.x & 63;
  const int w = threadIdx.x >> 6;
  const int lo = l & 15, quad = l >> 4;
  const int e0 = (blockIdx.x * 4 + w) * 16;

  const short8* WF1 = (const short8*)wfrag;
  const short8* WF2 = (const short8*)(wfrag + 16384);
  const short8* WF4 = (const short8*)(wfrag + 32768);

  // A-fragment rows (m = lo): edge at CSR position p
  int p = e0 + lo;
  int4 rp = rec[p];
  int sp = rp.x, tp = rp.y, ep = rp.z;
  if (l < 16) src_lds[w][l] = sp;   // wave-local, in-order DS pipe

  short8 niF[4], njF[4], eaF[3];
  {
    const short8* xr = (const short8*)(XB + (size_t)sp * C);
    const short8* yr = (const short8*)(XB + (size_t)tp * C);
    for (int s = 0; s < 4; ++s) { niF[s] = xr[s * 4 + quad]; njF[s] = yr[s * 4 + quad]; }
  }
  {
    const float* er = ea + (size_t)ep * EAC;     // 280B rows: 8B aligned
    const float2* ca = (const float2*)(er + quad * 8);
    const float2* cb = (const float2*)(er + 32 + quad * 8);
    float2 a0 = ca[0], a1 = ca[1], a2 = ca[2], a3 = ca[3];
    float2 b0 = cb[0], b1 = cb[1], b2 = cb[2], b3 = cb[3];
    short8 t0, t1, t2;
    t0[0] = (short)f2bf(a0.x); t0[1] = (short)f2bf(a0.y);
    t0[2] = (short)f2bf(a1.x); t0[3] = (short)f2bf(a1.y);
    t0[4] = (short)f2bf(a2.x); t0[5] = (short)f2bf(a2.y);
    t0[6] = (short)f2bf(a3.x); t0[7] = (short)f2bf(a3.y);
    t1[0] = (short)f2bf(b0.x); t1[1] = (short)f2bf(b0.y);
    t1[2] = (short)f2bf(b1.x); t1[3] = (short)f2bf(b1.y);
    t1[4] = (short)f2bf(b2.x); t1[5] = (short)f2bf(b2.y);
    t1[6] = (short)f2bf(b3.x); t1[7] = (short)f2bf(b3.y);
    for (int j = 0; j < 8; ++j) t2[j] = 0;
    if (quad == 0) {
      t2[0] = (short)f2bf(er[64]);
      mask_lds[w][lo] = (a0.x < 8.f) ? 1.f : 0.f;
    }
    eaF[0] = t0; eaF[1] = t1; eaF[2] = t2;
  }

  // C-layout metadata (row = quad*4+i at CSR position e0+quad*4+i)
  float maskv[4];
  int srcRow[4];
  for (int i = 0; i < 4; ++i) {
    maskv[i] = mask_lds[w][quad * 4 + i];   // wave-local RAW via in-order DS pipe
    srcRow[i] = src_lds[w][quad * 4 + i];
  }

  // f = elu(ni@WF1 + nj@WF2 + ea@WF4 + bf) * mask -> LDS (bf16)
  for (int t = 0; t < 8; ++t) {
    floatx4 acc = (floatx4){0.f, 0.f, 0.f, 0.f};
    for (int s = 0; s < 4; ++s)
      acc = __builtin_amdgcn_mfma_f32_16x16x32_bf16(niF[s], WF1[(s * 8 + t) * 64 + l], acc, 0, 0, 0);
    for (int s = 0; s < 4; ++s)
      acc = __builtin_amdgcn_mfma_f32_16x16x32_bf16(njF[s], WF2[(s * 8 + t) * 64 + l], acc, 0, 0, 0);
    for (int s = 0; s < 3; ++s)
      acc = __builtin_amdgcn_mfma_f32_16x16x32_bf16(eaF[s], WF4[(s * 8 + t) * 64 + l], acc, 0, 0, 0);
    float bias = bfv[lo + 16 * t];
    for (int i = 0; i < 4; ++i) {
      float v = fast_elu(acc[i] + bias);  // C/D: row=quad*4+i, col=lo+16t
      v *= maskv[i];
      f_lds[w][quad * 4 + i][lo + 16 * t] = f2bf(v);
    }
  }

  // a = f . M[src]; store (a, cf=exp(a)) per row; f stays as-is in LDS
  for (int i = 0; i < 4; ++i) {
    const short8 fv = *(const short8*)&f_lds[w][quad * 4 + i][lo * 8];
    const short8 mv = *(const short8*)(M + (size_t)srcRow[i] * C + lo * 8);
    float d = 0.f;
    for (int j = 0; j < 8; ++j)
      d += bf2f((unsigned short)fv[j]) * bf2f((unsigned short)mv[j]);
    d += __shfl_xor(d, 1);
    d += __shfl_xor(d, 2);
    d += __shfl_xor(d, 4);
    d += __shfl_xor(d, 8);
    float a = fast_tanh(d);               // Wm includes the 1/sqrt(C) scale
    if (lo == 0) acf_lds[w][quad * 4 + i] = make_float2(a, __expf(a));
  }

  // wave-local segmented reduction over the 16 CSR-sorted rows.
  // src sequence is non-decreasing; branch is wave-uniform (readfirstlane).
  // Each lane owns 2 columns; partial row flushed as ONE pk-bf16 atomic/lane.
  {
    const int col = l << 1;
    float acc0 = 0.f, acc1 = 0.f, accA = 0.f;
    int cur = __builtin_amdgcn_readfirstlane(src_lds[w][0]);
#pragma unroll
    for (int r = 0; r < 16; ++r) {
      int s_r = __builtin_amdgcn_readfirstlane(src_lds[w][r]);
      if (s_r != cur) {
        atomic_pk_add_bf16(Pb + (size_t)cur * C + col, acc0, acc1);
        if (l == 0) atomicAdd(a_sum + cur, accA);
        acc0 = acc1 = accA = 0.f;
        cur = s_r;
      }
      unsigned v = *(const unsigned*)&f_lds[w][r][col];
      float2 acf = acf_lds[w][r];         // broadcast read
      acc0 = fmaf(acf.y, bf2f((unsigned short)(v & 0xFFFFu)), acc0);
      acc1 = fmaf(acf.y, bf2f((unsigned short)(v >> 16)), acc1);
      accA += acf.x;
    }
    atomic_pk_add_bf16(Pb + (size_t)cur * C + col, acc0, acc1);
    if (l == 0) atomicAdd(a_sum + cur, accA);
  }
}

// ---------------- dense node update: out = (x + exp(-a_sum)*P) @ Wu + bu -----
__global__ __launch_bounds__(256) void node_kernel(
    const float* __restrict__ x, const unsigned short* __restrict__ Pb,
    const float* __restrict__ a_sum, const float* __restrict__ Wu,
    const float* __restrict__ bu, float* __restrict__ out) {
  __shared__ float rows[32][129];
  int b0 = blockIdx.x * 32;
  for (int idx = threadIdx.x; idx < 32 * 128; idx += 256) {
    int r = idx >> 7, i = idx & 127;
    int n = b0 + r;
    float v = 0.f;
    if (n < NN) v = x[(size_t)n * C + i] + __expf(-a_sum[n]) * bf2f(Pb[(size_t)n * C + i]);
    rows[r][i] = v;
  }
  __syncthreads();
  int tr = threadIdx.x >> 4;
  int tc = threadIdx.x & 15;
  floatx4 a00 = (floatx4){0,0,0,0}, a01 = a00, a10 = a00, a11 = a00;
  for (int i = 0; i < C; ++i) {
    float r0 = rows[tr * 2][i], r1 = rows[tr * 2 + 1][i];
    const floatx4* wr = (const floatx4*)(Wu + (size_t)i * C + tc * 8);
    floatx4 w0 = wr[0], w1 = wr[1];
    a00 += w0 * r0; a01 += w1 * r0;
    a10 += w0 * r1; a11 += w1 * r1;
  }
  const floatx4* bv = (const floatx4*)(bu + tc * 8);
  floatx4 bb0 = bv[0], bb1 = bv[1];
  int n0 = b0 + tr * 2;
  if (n0 < NN) {
    floatx4* o = (floatx4*)(out + (size_t)n0 * C + tc * 8);
    o[0] = a00 + bb0; o[1] = a01 + bb1;
  }
  if (n0 + 1 < NN) {
    floatx4* o = (floatx4*)(out + (size_t)(n0 + 1) * C + tc * 8);
    o[0] = a10 + bb0; o[1] = a11 + bb1;
  }
}

// ---------------- fallback: natural-order edge kernel with atomic scatter ----
__global__ __launch_bounds__(256, 4) void fb_edge_kernel(
    const float* __restrict__ x, const int* __restrict__ src,
    const int* __restrict__ tgt, const float* __restrict__ ea,
    const float* __restrict__ bfv, const unsigned short* __restrict__ wfrag,
    const unsigned short* __restrict__ M, float* __restrict__ a_sum,
    float* __restrict__ P) {
  __shared__ unsigned short f_lds[4][16][136];
  __shared__ float mask_lds[4][16];
  const int l = threadIdx.x & 63;
  const int w = threadIdx.x >> 6;
  const int lo = l & 15, quad = l >> 4;
  const int e0 = (blockIdx.x * 4 + w) * 16;
  const short8* WF1 = (const short8*)wfrag;
  const short8* WF2 = (const short8*)(wfrag + 16384);
  const short8* WF4 = (const short8*)(wfrag + 32768);

  int p = e0 + lo;
  int sp = src[p], tp = tgt[p];
  short8 niF[4], njF[4], eaF[3];
  {
    const float* xr = x + (size_t)sp * C;
    const float* yr = x + (size_t)tp * C;
    for (int s = 0; s < 4; ++s) {
      int kb = s * 32 + quad * 8;
      const floatx4* xv = (const floatx4*)(xr + kb);
      const floatx4* yv = (const floatx4*)(yr + kb);
      floatx4 x0 = xv[0], x1 = xv[1], y0 = yv[0], y1 = yv[1];
      short8 a, b;
      for (int j = 0; j < 4; ++j) { a[j] = (short)f2bf(x0[j]); a[4 + j] = (short)f2bf(x1[j]); }
      for (int j = 0; j < 4; ++j) { b[j] = (short)f2bf(y0[j]); b[4 + j] = (short)f2bf(y1[j]); }
      niF[s] = a; njF[s] = b;
    }
    const float* er = ea + (size_t)p * EAC;
    const float2* ca = (const float2*)(er + quad * 8);
    const float2* cb = (const float2*)(er + 32 + quad * 8);
    float2 a0 = ca[0], a1 = ca[1], a2 = ca[2], a3 = ca[3];
    float2 b0 = cb[0], b1 = cb[1], b2 = cb[2], b3 = cb[3];
    short8 t0, t1, t2;
    t0[0] = (short)f2bf(a0.x); t0[1] = (short)f2bf(a0.y);
    t0[2] = (short)f2bf(a1.x); t0[3] = (short)f2bf(a1.y);
    t0[4] = (short)f2bf(a2.x); t0[5] = (short)f2bf(a2.y);
    t0[6] = (short)f2bf(a3.x); t0[7] = (short)f2bf(a3.y);
    t1[0] = (short)f2bf(b0.x); t1[1] = (short)f2bf(b0.y);
    t1[2] = (short)f2bf(b1.x); t1[3] = (short)f2bf(b1.y);
    t1[4] = (short)f2bf(b2.x); t1[5] = (short)f2bf(b2.y);
    t1[6] = (short)f2bf(b3.x); t1[7] = (short)f2bf(b3.y);
    for (int j = 0; j < 8; ++j) t2[j] = 0;
    if (quad == 0) {
      t2[0] = (short)f2bf(er[64]);
      mask_lds[w][lo] = (a0.x < 8.f) ? 1.f : 0.f;
    }
    eaF[0] = t0; eaF[1] = t1; eaF[2] = t2;
  }
  float maskv[4];
  int srcRow[4];
  for (int i = 0; i < 4; ++i) {
    maskv[i] = mask_lds[w][quad * 4 + i];
    srcRow[i] = src[e0 + quad * 4 + i];
  }
  for (int t = 0; t < 8; ++t) {
    floatx4 acc = (floatx4){0.f, 0.f, 0.f, 0.f};
    for (int s = 0; s < 4; ++s)
      acc = __builtin_amdgcn_mfma_f32_16x16x32_bf16(niF[s], WF1[(s * 8 + t) * 64 + l], acc, 0, 0, 0);
    for (int s = 0; s < 4; ++s)
      acc = __builtin_amdgcn_mfma_f32_16x16x32_bf16(njF[s], WF2[(s * 8 + t) * 64 + l], acc, 0, 0, 0);
    for (int s = 0; s < 3; ++s)
      acc = __builtin_amdgcn_mfma_f32_16x16x32_bf16(eaF[s], WF4[(s * 8 + t) * 64 + l], acc, 0, 0, 0);
    float bias = bfv[lo + 16 * t];
    for (int i = 0; i < 4; ++i) {
      float v = fast_elu(acc[i] + bias);
      v *= maskv[i];
      f_lds[w][quad * 4 + i][lo + 16 * t] = f2bf(v);
    }
  }
  for (int i = 0; i < 4; ++i) {
    const short8 fv = *(const short8*)&f_lds[w][quad * 4 + i][lo * 8];
    const short8 mv = *(const short8*)(M + (size_t)srcRow[i] * C + lo * 8);
    float d = 0.f;
    for (int j = 0; j < 8; ++j)
      d += bf2f((unsigned short)fv[j]) * bf2f((unsigned short)mv[j]);
    d += __shfl_xor(d, 1);
    d += __shfl_xor(d, 2);
    d += __shfl_xor(d, 4);
    d += __shfl_xor(d, 8);
    float a = fast_tanh(d);
    float cf = __expf(a);
    if (lo == 0) atomicAdd(a_sum + srcRow[i], a);
    float* Prow = P + (size_t)srcRow[i] * C;
    for (int j = 0; j < 8; ++j)
      atomicAdd(Prow + lo * 8 + j, cf * bf2f((unsigned short)fv[j]));
  }
}

__global__ __launch_bounds__(256) void fb_node_kernel(
    const float* __restrict__ x, const float* __restrict__ P,
    const float* __restrict__ a_sum, const float* __restrict__ Wu,
    const float* __restrict__ bu, float* __restrict__ out) {
  __shared__ float rows[32][129];
  int b0 = blockIdx.x * 32;
  for (int idx = threadIdx.x; idx < 32 * 128; idx += 256) {
    int r = idx >> 7, i = idx & 127;
    int n = b0 + r;
    float v = 0.f;
    if (n < NN) v = x[(size_t)n * C + i] + expf(-a_sum[n]) * P[(size_t)n * C + i];
    rows[r][i] = v;
  }
  __syncthreads();
  int tr = threadIdx.x >> 4;
  int tc = threadIdx.x & 15;
  floatx4 a00 = (floatx4){0,0,0,0}, a01 = a00, a10 = a00, a11 = a00;
  for (int i = 0; i < C; ++i) {
    float r0 = rows[tr * 2][i], r1 = rows[tr * 2 + 1][i];
    const floatx4* wr = (const floatx4*)(Wu + (size_t)i * C + tc * 8);
    floatx4 w0 = wr[0], w1 = wr[1];
    a00 += w0 * r0; a01 += w1 * r0;
    a10 += w0 * r1; a11 += w1 * r1;
  }
  const floatx4* bv = (const floatx4*)(bu + tc * 8);
  floatx4 bb0 = bv[0], bb1 = bv[1];
  int n0 = b0 + tr * 2;
  if (n0 < NN) {
    floatx4* o = (floatx4*)(out + (size_t)n0 * C + tc * 8);
    o[0] = a00 + bb0; o[1] = a01 + bb1;
  }
  if (n0 + 1 < NN) {
    floatx4* o = (floatx4*)(out + (size_t)(n0 + 1) * C + tc * 8);
    o[0] = a10 + bb0; o[1] = a11 + bb1;
  }
}

extern "C" void kernel_launch(void* const* d_in, const int* in_sizes, int n_in,
                              void* d_out, int out_size, void* d_ws, size_t ws_size,
                              hipStream_t stream) {
  const float* x  = (const float*)d_in[0];
  const int*   ei = (const int*)d_in[1];
  const float* ea = (const float*)d_in[2];
  const float* Wf = (const float*)d_in[3];
  const float* bf = (const float*)d_in[4];
  const float* Wq = (const float*)d_in[5];
  const float* Wk = (const float*)d_in[6];
  const float* Wa = (const float*)d_in[7];
  const float* Wu = (const float*)d_in[8];
  const float* bu = (const float*)d_in[9];
  float* out = (float*)d_out;
  const int* src = ei;
  const int* tgt = ei + E_EDGES;

  size_t off = 0;
  auto take = [&](size_t n) { size_t r = off; off += (n + 255) & ~(size_t)255; return r; };
  // Pb (bf16), a_sum, deg, cursor contiguous -> single memset
  size_t oP    = take((size_t)NN * C * 2);        // 12.8 MB bf16
  size_t oAs   = take((size_t)NN * 4);
  size_t oDeg  = take((size_t)NN * 4);
  size_t oCur  = take((size_t)NN * 4);
  size_t oOffs = take((size_t)NN * 4);
  size_t oBs   = take((size_t)NB * 4);
  size_t oBb   = take((size_t)NB * 4);
  size_t oRec  = take((size_t)E_EDGES * 16);      // packed {src,tgt,e,0}
  size_t oWfr  = take((size_t)45056 * 2);
  size_t oWm   = take((size_t)C * C * 4);
  size_t oM    = take((size_t)NN * C * 2);
  size_t oXB   = take((size_t)NN * C * 2);
  size_t need = off;

  if (ws_size >= need) {
    unsigned short* Pb = (unsigned short*)((char*)d_ws + oP);
    float* a_sum = (float*)((char*)d_ws + oAs);
    int* deg = (int*)((char*)d_ws + oDeg);
    int* cursor = (int*)((char*)d_ws + oCur);
    int* offs = (int*)((char*)d_ws + oOffs);
    int* bsum = (int*)((char*)d_ws + oBs);
    int* bbase = (int*)((char*)d_ws + oBb);
    int4* rec = (int4*)((char*)d_ws + oRec);
    unsigned short* wfrag = (unsigned short*)((char*)d_ws + oWfr);
    float* Wm = (float*)((char*)d_ws + oWm);
    unsigned short* M = (unsigned short*)((char*)d_ws + oM);
    unsigned short* XB = (unsigned short*)((char*)d_ws + oXB);

    hipMemsetAsync(Pb, 0, oOffs - oP, stream);   // Pb + a_sum + deg + cursor
    setup_kernel<<<3365, 256, 0, stream>>>(Wf, Wq, Wk, Wa, src, wfrag, Wm, deg);
    m_kernel<<<(NN + 31) / 32, 256, 0, stream>>>(x, Wm, M, XB);
    scan1_kernel<<<NB, 256, 0, stream>>>(deg, offs, bsum);
    scan2_kernel<<<1, 256, 0, stream>>>(bsum, bbase);
    pos_kernel<<<E_EDGES / 256, 256, 0, stream>>>(src, tgt, offs, bbase, cursor, rec);
    edge_kernel<<<E_EDGES / 64, 256, 0, stream>>>(XB, ea, bf, wfrag, rec, M, Pb, a_sum);
    node_kernel<<<(NN + 31) / 32, 256, 0, stream>>>(x, Pb, a_sum, Wu, bu, out);
  } else {
    size_t f = 0;
    auto tk = [&](size_t n) { size_t r = f; f += (n + 255) & ~(size_t)255; return r; };
    size_t fP = tk((size_t)NN * C * 4);
    size_t fAs = tk((size_t)NN * 4);
    size_t fDeg = tk((size_t)NN * 4);
    size_t fWfr = tk((size_t)45056 * 2);
    size_t fWm = tk((size_t)C * C * 4);
    size_t fM = tk((size_t)NN * C * 2);
    float* P = (float*)((char*)d_ws + fP);
    float* a_sum = (float*)((char*)d_ws + fAs);
    int* deg = (int*)((char*)d_ws + fDeg);
    unsigned short* wfrag = (unsigned short*)((char*)d_ws + fWfr);
    float* Wm = (float*)((char*)d_ws + fWm);
    unsigned short* M = (unsigned short*)((char*)d_ws + fM);
    hipMemsetAsync(P, 0, (size_t)NN * C * 4 + 256 + NN * 4, stream);
    setup_kernel<<<3365, 256, 0, stream>>>(Wf, Wq, Wk, Wa, src, wfrag, Wm, deg);
    m_kernel<<<(NN + 31) / 32, 256, 0, stream>>>(x, Wm, M, (unsigned short*)P);
    hipMemsetAsync(P, 0, (size_t)NN * C * 4, stream);  // re-zero P after XB scribble
    fb_edge_kernel<<<E_EDGES / 64, 256, 0, stream>>>(x, src, tgt, ea, bf, wfrag, M,
                                                     a_sum, P);
    fb_node_kernel<<<(NN + 31) / 32, 256, 0, stream>>>(x, P, a_sum, Wu, bu, out);
  }
}